// Round 4
// baseline (794.860 us; speedup 1.0000x reference)
//
#include <hip/hip_runtime.h>
#include <stdint.h>

#define T_TOK 4096
#define DIM   2048
#define INTER 1024
#define NE    9        // 8 routed + 1 shared (as expert 8)
#define NPAIR 12288    // T_TOK * 3 slots

typedef float v4f __attribute__((ext_vector_type(4)));
typedef short v8s __attribute__((ext_vector_type(8)));   // 8 bf16 in 4 VGPRs

__device__ __forceinline__ unsigned short f2bf(float f) {
    unsigned u = __float_as_uint(f);
    u += 0x7fffu + ((u >> 16) & 1u);           // RNE
    return (unsigned short)(u >> 16);
}

__device__ __forceinline__ void gload_lds16(const void* g, void* l) {
    __builtin_amdgcn_global_load_lds(
        (const __attribute__((address_space(1))) void*)g,
        (__attribute__((address_space(3))) void*)l, 16, 0, 0);
}

// ---------------- weight convert: 3 matrices in one launch ----------------
__global__ __launch_bounds__(256) void cvt_w_kernel(
        const float* __restrict__ w1,  const float* __restrict__ ws1, unsigned short* __restrict__ w1b,
        const float* __restrict__ w3,  const float* __restrict__ ws3, unsigned short* __restrict__ w3b,
        const float* __restrict__ w2,  const float* __restrict__ ws2, unsigned short* __restrict__ w2b) {
    int which = blockIdx.y;
    const float* wmain = (which == 0) ? w1  : (which == 1) ? w3  : w2;
    const float* wsh   = (which == 0) ? ws1 : (which == 1) ? ws3 : ws2;
    unsigned short* dst = (which == 0) ? w1b : (which == 1) ? w3b : w2b;
    long long i = (long long)blockIdx.x * 256 + threadIdx.x; // vec4 index
    long long base = i * 4;
    int e = (int)(base >> 21);
    long long within = base & ((1ll << 21) - 1);
    const float* src = (e < 8) ? (wmain + ((long long)e << 21) + within) : (wsh + within);
    float4 f = *(const float4*)src;
    ushort4 u;
    u.x = f2bf(f.x); u.y = f2bf(f.y); u.z = f2bf(f.z); u.w = f2bf(f.w);
    *(ushort4*)(dst + base) = u;
}

// ---------------- gate (fp32 routing, fused x->bf16 convert, NO atomics) ----------------
__global__ __launch_bounds__(256) void gate_kernel(const float* __restrict__ x,
                                                   const float* __restrict__ gw,
                                                   float* __restrict__ wt,
                                                   int* __restrict__ ei,
                                                   unsigned short* __restrict__ xb) {
    __shared__ float xs[DIM];
    __shared__ float lg[8];
    int t = blockIdx.x;
    const float* xrow = x + (size_t)t * DIM;
    for (int i = threadIdx.x; i < DIM / 4; i += 256)
        ((float4*)xs)[i] = ((const float4*)xrow)[i];
    __syncthreads();
    for (int i = threadIdx.x; i < DIM / 4; i += 256) {
        float4 f = ((const float4*)xs)[i];
        ushort4 u;
        u.x = f2bf(f.x); u.y = f2bf(f.y); u.z = f2bf(f.z); u.w = f2bf(f.w);
        ((ushort4*)(xb + (size_t)t * DIM))[i] = u;
    }
    int e = threadIdx.x >> 5;
    int l = threadIdx.x & 31;
    const float* g = gw + (size_t)e * DIM;
    float p = 0.f;
    #pragma unroll 8
    for (int d = l; d < DIM; d += 32) p += xs[d] * g[d];
    for (int m = 16; m >= 1; m >>= 1) p += __shfl_xor(p, m, 32);
    if (l == 0) lg[e] = p;
    __syncthreads();
    if (threadIdx.x == 0) {
        float mx = lg[0];
        for (int i = 1; i < 8; i++) mx = fmaxf(mx, lg[i]);
        float pr[8], s = 0.f;
        for (int i = 0; i < 8; i++) { pr[i] = __expf(lg[i] - mx); s += pr[i]; }
        float inv = 1.f / s;
        float b1 = -1.f, b2 = -1.f; int i1 = 0, i2 = 0;
        for (int i = 0; i < 8; i++) {
            float v = pr[i] * inv;
            if (v > b1)      { b2 = b1; i2 = i1; b1 = v; i1 = i; }
            else if (v > b2) { b2 = v;  i2 = i; }
        }
        wt[t * 3 + 0] = b1; wt[t * 3 + 1] = b2; wt[t * 3 + 2] = 1.f;
        ei[t * 3 + 0] = i1; ei[t * 3 + 1] = i2; ei[t * 3 + 2] = 8;
    }
}

// meta layout: [0..9) counts, [9..18) cursors, [18..27) offsets
__global__ void zero_meta_kernel(int* meta) {
    if (threadIdx.x < 18) meta[threadIdx.x] = 0;
}
// block-aggregated expert counting: 16 blocks x 9 global atomics total
__global__ __launch_bounds__(256) void count_kernel(const int* __restrict__ ei,
                                                    int* __restrict__ meta) {
    __shared__ int lcnt[NE];
    if (threadIdx.x < NE) lcnt[threadIdx.x] = 0;
    __syncthreads();
    int t = blockIdx.x * 256 + threadIdx.x;
    #pragma unroll
    for (int s = 0; s < 3; s++) atomicAdd(&lcnt[ei[t * 3 + s]], 1);
    __syncthreads();
    if (threadIdx.x < NE) atomicAdd(&meta[threadIdx.x], lcnt[threadIdx.x]);
}
__global__ void scan_meta_kernel(int* meta) {
    if (threadIdx.x == 0) {
        int a = 0;
        for (int e = 0; e < NE; e++) { meta[18 + e] = a; a += meta[e]; }
    }
}
// block-aggregated placement; also writes token->slot map for the combine pass
__global__ __launch_bounds__(256) void fill_kernel(const int* __restrict__ ei,
                                                   const float* __restrict__ wt,
                                                   int* __restrict__ meta,
                                                   int* __restrict__ pair_tok,
                                                   float* __restrict__ pair_w,
                                                   int* __restrict__ slots) {
    __shared__ int lcnt[NE], lbase[NE];
    if (threadIdx.x < NE) lcnt[threadIdx.x] = 0;
    __syncthreads();
    int t = blockIdx.x * 256 + threadIdx.x;
    int es[3], lp[3];
    #pragma unroll
    for (int s = 0; s < 3; s++) {
        es[s] = ei[t * 3 + s];
        lp[s] = atomicAdd(&lcnt[es[s]], 1);
    }
    __syncthreads();
    if (threadIdx.x < NE)
        lbase[threadIdx.x] = atomicAdd(&meta[9 + threadIdx.x], lcnt[threadIdx.x]);
    __syncthreads();
    #pragma unroll
    for (int s = 0; s < 3; s++) {
        int g = meta[18 + es[s]] + lbase[es[s]] + lp[s];
        pair_tok[g] = t;
        pair_w[g] = wt[t * 3 + s];
        slots[t * 3 + s] = g;
    }
}

// ---------------- GEMM1: G[p,i] = silu(x.w1^T) * (x.w3^T) * route_w, bf16 out ----------------
// BM=128, BN=64, BK=64, 256 threads (4 waves, 2x2), dual accumulator (w1,w3)
// Grid: x = m-block capacity (fastest -> weight slice stays L2-hot over its m-sweep),
//       y = n-block, z = expert
__global__ __launch_bounds__(256) void gemm1_kernel(
        const unsigned short* __restrict__ xb,
        const unsigned short* __restrict__ w1b,
        const unsigned short* __restrict__ w3b,
        unsigned short* __restrict__ G,
        const int* __restrict__ meta,
        const int* __restrict__ pair_tok,
        const float* __restrict__ pair_w) {
    int e = blockIdx.z;
    int cnt = meta[e];
    int m0 = blockIdx.x * 128;
    if (m0 >= cnt) return;
    int off = meta[18 + e];
    int n0 = blockIdx.y * 64;

    __shared__ __align__(16) unsigned short As[128 * 64];
    __shared__ __align__(16) unsigned short B1s[64 * 64];
    __shared__ __align__(16) unsigned short B3s[64 * 64];

    int tid = threadIdx.x;
    int wave = tid >> 6, lane = tid & 63;
    int kc = (lane & 7) ^ (lane >> 3);          // XOR phase: j-invariant

    const unsigned short* gsrcA[8];
    const unsigned short* bbase = nullptr;
    unsigned short* lbase = nullptr;
    if (wave < 2) {
        #pragma unroll
        for (int j = 0; j < 8; j++) {
            int row = (wave * 8 + j) * 8 + (lane >> 3);
            int p = m0 + row; p = p < cnt ? p : cnt - 1;
            int tok = pair_tok[off + p];
            gsrcA[j] = xb + (size_t)tok * DIM + kc * 8;
        }
    } else {
        const unsigned short* wsrc = (wave == 2) ? w1b : w3b;
        lbase = (wave == 2) ? B1s : B3s;
        bbase = wsrc + ((size_t)e * INTER + n0 + (lane >> 3)) * DIM + kc * 8;
    }

    int wm = wave >> 1, wn = wave & 1;
    int mb = wm * 64, nb = wn * 32;
    v4f zero4 = {0.f, 0.f, 0.f, 0.f};
    v4f acc1[4][2], acc3[4][2];
    #pragma unroll
    for (int i = 0; i < 4; i++)
        #pragma unroll
        for (int j = 0; j < 2; j++) { acc1[i][j] = zero4; acc3[i][j] = zero4; }

    for (int k0 = 0; k0 < DIM; k0 += 64) {
        if (wave < 2) {
            #pragma unroll
            for (int j = 0; j < 8; j++)
                gload_lds16(gsrcA[j] + k0, &As[(wave * 8 + j) * 512]);
        } else {
            #pragma unroll
            for (int j = 0; j < 8; j++)
                gload_lds16(bbase + (size_t)j * 8 * DIM + k0, &lbase[j * 512]);
        }
        __syncthreads();
        #pragma unroll
        for (int s = 0; s < 2; s++) {
            int kk = s * 4 + (lane >> 4);
            v8s a[4], b1[2], b3[2];
            #pragma unroll
            for (int mt = 0; mt < 4; mt++) {
                int r = mb + mt * 16 + (lane & 15);
                a[mt] = *(const v8s*)&As[r * 64 + ((kk ^ (r & 7)) << 3)];
            }
            #pragma unroll
            for (int nt = 0; nt < 2; nt++) {
                int n = nb + nt * 16 + (lane & 15);
                int o = n * 64 + ((kk ^ (n & 7)) << 3);
                b1[nt] = *(const v8s*)&B1s[o];
                b3[nt] = *(const v8s*)&B3s[o];
            }
            #pragma unroll
            for (int mt = 0; mt < 4; mt++)
                #pragma unroll
                for (int nt = 0; nt < 2; nt++) {
                    acc1[mt][nt] = __builtin_amdgcn_mfma_f32_16x16x32_bf16(a[mt], b1[nt], acc1[mt][nt], 0, 0, 0);
                    acc3[mt][nt] = __builtin_amdgcn_mfma_f32_16x16x32_bf16(a[mt], b3[nt], acc3[mt][nt], 0, 0, 0);
                }
        }
        __syncthreads();
    }

    #pragma unroll
    for (int mt = 0; mt < 4; mt++) {
        #pragma unroll
        for (int r = 0; r < 4; r++) {
            int row = mb + mt * 16 + ((lane >> 4) << 2) + r;
            int p = m0 + row;
            if (p < cnt) {
                float w = pair_w[off + p];
                size_t gbase = (size_t)(off + p) * INTER + n0 + nb;
                #pragma unroll
                for (int nt = 0; nt < 2; nt++) {
                    float h1 = acc1[mt][nt][r];
                    float h3 = acc3[mt][nt][r];
                    float gv = h1 / (1.f + __expf(-h1)) * h3 * w;
                    G[gbase + nt * 16 + (lane & 15)] = f2bf(gv);
                }
            }
        }
    }
}

// ---------------- GEMM2: eo[p,d] = G[p,:] . w2[e][d,:]  (bf16, non-atomic) ----------------
// BM=128, BN=128, BK=64, 256 threads (4 waves, 2x2); grid x = m-blocks (fastest)
__global__ __launch_bounds__(256) void gemm2_kernel(
        const unsigned short* __restrict__ G,
        const unsigned short* __restrict__ w2b,
        unsigned short* __restrict__ eo,
        const int* __restrict__ meta) {
    int e = blockIdx.z;
    int cnt = meta[e];
    int m0 = blockIdx.x * 128;
    if (m0 >= cnt) return;
    int off = meta[18 + e];
    int n0 = blockIdx.y * 128;

    __shared__ __align__(16) unsigned short As[128 * 64];
    __shared__ __align__(16) unsigned short Bs[128 * 64];

    int tid = threadIdx.x;
    int wave = tid >> 6, lane = tid & 63;
    int kc = (lane & 7) ^ (lane >> 3);

    const unsigned short* gsrcA[8];
    const unsigned short* bbase = nullptr;
    if (wave < 2) {
        #pragma unroll
        for (int j = 0; j < 8; j++) {
            int row = (wave * 8 + j) * 8 + (lane >> 3);
            int p = m0 + row; p = p < cnt ? p : cnt - 1;
            gsrcA[j] = G + (size_t)(off + p) * INTER + kc * 8;
        }
    } else {
        int g0 = (wave - 2) * 64;
        bbase = w2b + ((size_t)e * DIM + n0 + g0 + (lane >> 3)) * INTER + kc * 8;
    }

    int wm = wave >> 1, wn = wave & 1;
    int mb = wm * 64, nbw = wn * 64;
    v4f zero4 = {0.f, 0.f, 0.f, 0.f};
    v4f acc[4][4];
    #pragma unroll
    for (int i = 0; i < 4; i++)
        #pragma unroll
        for (int j = 0; j < 4; j++) acc[i][j] = zero4;

    for (int k0 = 0; k0 < INTER; k0 += 64) {
        if (wave < 2) {
            #pragma unroll
            for (int j = 0; j < 8; j++)
                gload_lds16(gsrcA[j] + k0, &As[(wave * 8 + j) * 512]);
        } else {
            int g0 = (wave - 2) * 8;
            #pragma unroll
            for (int j = 0; j < 8; j++)
                gload_lds16(bbase + (size_t)j * 8 * INTER + k0, &Bs[(g0 + j) * 512]);
        }
        __syncthreads();
        #pragma unroll
        for (int s = 0; s < 2; s++) {
            int kk = s * 4 + (lane >> 4);
            v8s a[4], b[4];
            #pragma unroll
            for (int mt = 0; mt < 4; mt++) {
                int r = mb + mt * 16 + (lane & 15);
                a[mt] = *(const v8s*)&As[r * 64 + ((kk ^ (r & 7)) << 3)];
            }
            #pragma unroll
            for (int nt = 0; nt < 4; nt++) {
                int n = nbw + nt * 16 + (lane & 15);
                b[nt] = *(const v8s*)&Bs[n * 64 + ((kk ^ (n & 7)) << 3)];
            }
            #pragma unroll
            for (int mt = 0; mt < 4; mt++)
                #pragma unroll
                for (int nt = 0; nt < 4; nt++)
                    acc[mt][nt] = __builtin_amdgcn_mfma_f32_16x16x32_bf16(a[mt], b[nt], acc[mt][nt], 0, 0, 0);
        }
        __syncthreads();
    }

    #pragma unroll
    for (int mt = 0; mt < 4; mt++) {
        #pragma unroll
        for (int r = 0; r < 4; r++) {
            int row = mb + mt * 16 + ((lane >> 4) << 2) + r;
            int p = m0 + row;
            if (p < cnt) {
                unsigned short* obase = eo + (size_t)(off + p) * DIM + n0 + nbw;
                #pragma unroll
                for (int nt = 0; nt < 4; nt++)
                    obase[nt * 16 + (lane & 15)] = f2bf(acc[mt][nt][r]);
            }
        }
    }
}

// ---------------- combine: out[t,:] = eo[p1,:] + eo[p2,:] + eo[p3,:] ----------------
__global__ __launch_bounds__(256) void combine_kernel(const unsigned short* __restrict__ eo,
                                                      const int* __restrict__ slots,
                                                      float* __restrict__ out) {
    int t = blockIdx.x;
    int p0 = slots[t * 3 + 0], p1 = slots[t * 3 + 1], p2 = slots[t * 3 + 2];
    const ushort4* r0 = (const ushort4*)(eo + (size_t)p0 * DIM);
    const ushort4* r1 = (const ushort4*)(eo + (size_t)p1 * DIM);
    const ushort4* r2 = (const ushort4*)(eo + (size_t)p2 * DIM);
    float4* o = (float4*)(out + (size_t)t * DIM);
    for (int i = threadIdx.x; i < DIM / 4; i += 256) {
        ushort4 a = r0[i], b = r1[i], c = r2[i];
        float4 v;
        v.x = __uint_as_float((unsigned)a.x << 16) + __uint_as_float((unsigned)b.x << 16) + __uint_as_float((unsigned)c.x << 16);
        v.y = __uint_as_float((unsigned)a.y << 16) + __uint_as_float((unsigned)b.y << 16) + __uint_as_float((unsigned)c.y << 16);
        v.z = __uint_as_float((unsigned)a.z << 16) + __uint_as_float((unsigned)b.z << 16) + __uint_as_float((unsigned)c.z << 16);
        v.w = __uint_as_float((unsigned)a.w << 16) + __uint_as_float((unsigned)b.w << 16) + __uint_as_float((unsigned)c.w << 16);
        o[i] = v;
    }
}

// ---------------- launch ----------------
extern "C" void kernel_launch(void* const* d_in, const int* in_sizes, int n_in,
                              void* d_out, int out_size, void* d_ws, size_t ws_size,
                              hipStream_t stream) {
    const float* x   = (const float*)d_in[0];
    const float* gw  = (const float*)d_in[1];
    const float* w1  = (const float*)d_in[2];
    const float* w2  = (const float*)d_in[3];
    const float* w3  = (const float*)d_in[4];
    const float* ws1 = (const float*)d_in[5];
    const float* ws2 = (const float*)d_in[6];
    const float* ws3 = (const float*)d_in[7];
    float* out = (float*)d_out;

    char* p = (char*)d_ws;
    auto alloc = [&](size_t bytes) {
        void* r = (void*)p;
        p += (bytes + 255) & ~(size_t)255;
        return r;
    };
    unsigned short* xb  = (unsigned short*)alloc((size_t)T_TOK * DIM * 2);
    unsigned short* w1b = (unsigned short*)alloc((size_t)NE * INTER * DIM * 2);
    unsigned short* w3b = (unsigned short*)alloc((size_t)NE * INTER * DIM * 2);
    unsigned short* w2b = (unsigned short*)alloc((size_t)NE * DIM * INTER * 2);
    unsigned short* G   = (unsigned short*)alloc((size_t)NPAIR * INTER * 2);
    int*   ei    = (int*)alloc((size_t)T_TOK * 3 * 4);
    float* wt    = (float*)alloc((size_t)T_TOK * 3 * 4);
    int*   ptok  = (int*)alloc((size_t)NPAIR * 4);
    float* pw    = (float*)alloc((size_t)NPAIR * 4);
    int*   slots = (int*)alloc((size_t)NPAIR * 4);
    int*   meta  = (int*)alloc(32 * 4);
    // eo (12288 x 2048 bf16 = 50.3 MB) aliases w1b+w3b (75.5 MB): dead after gemm1
    unsigned short* eo = w1b;

    zero_meta_kernel<<<1, 32, 0, stream>>>(meta);
    int wgrid = (NE * INTER * DIM / 4) / 256;   // 18432
    cvt_w_kernel<<<dim3(wgrid, 3), 256, 0, stream>>>(w1, ws1, w1b, w3, ws3, w3b, w2, ws2, w2b);
    gate_kernel<<<T_TOK, 256, 0, stream>>>(x, gw, wt, ei, xb);
    count_kernel<<<T_TOK / 256, 256, 0, stream>>>(ei, meta);
    scan_meta_kernel<<<1, 1, 0, stream>>>(meta);
    fill_kernel<<<T_TOK / 256, 256, 0, stream>>>(ei, wt, meta, ptok, pw, slots);
    gemm1_kernel<<<dim3(32, INTER / 64, NE), 256, 0, stream>>>(xb, w1b, w3b, G, meta, ptok, pw);
    gemm2_kernel<<<dim3(32, DIM / 128, NE), 256, 0, stream>>>(G, w2b, eo, meta);
    combine_kernel<<<T_TOK, 256, 0, stream>>>(eo, slots, out);
}

// Round 5
// 516.525 us; speedup vs baseline: 1.5389x; 1.5389x over previous
//
#include <hip/hip_runtime.h>
#include <stdint.h>

#define T_TOK 4096
#define DIM   2048
#define INTER 1024
#define NE    9        // 8 routed + 1 shared (as expert 8)
#define NPAIR 12288    // T_TOK * 3 slots

typedef float v4f __attribute__((ext_vector_type(4)));
typedef short v8s __attribute__((ext_vector_type(8)));   // 8 bf16 in 4 VGPRs

__device__ __forceinline__ unsigned short f2bf(float f) {
    unsigned u = __float_as_uint(f);
    u += 0x7fffu + ((u >> 16) & 1u);           // RNE
    return (unsigned short)(u >> 16);
}

__device__ __forceinline__ void gload_lds16(const void* g, void* l) {
    __builtin_amdgcn_global_load_lds(
        (const __attribute__((address_space(1))) void*)g,
        (__attribute__((address_space(3))) void*)l, 16, 0, 0);
}

// ---------------- weight convert: 3 matrices in one launch ----------------
__global__ __launch_bounds__(256) void cvt_w_kernel(
        const float* __restrict__ w1,  const float* __restrict__ ws1, unsigned short* __restrict__ w1b,
        const float* __restrict__ w3,  const float* __restrict__ ws3, unsigned short* __restrict__ w3b,
        const float* __restrict__ w2,  const float* __restrict__ ws2, unsigned short* __restrict__ w2b) {
    int which = blockIdx.y;
    const float* wmain = (which == 0) ? w1  : (which == 1) ? w3  : w2;
    const float* wsh   = (which == 0) ? ws1 : (which == 1) ? ws3 : ws2;
    unsigned short* dst = (which == 0) ? w1b : (which == 1) ? w3b : w2b;
    long long i = (long long)blockIdx.x * 256 + threadIdx.x; // vec4 index
    long long base = i * 4;
    int e = (int)(base >> 21);
    long long within = base & ((1ll << 21) - 1);
    const float* src = (e < 8) ? (wmain + ((long long)e << 21) + within) : (wsh + within);
    float4 f = *(const float4*)src;
    ushort4 u;
    u.x = f2bf(f.x); u.y = f2bf(f.y); u.z = f2bf(f.z); u.w = f2bf(f.w);
    *(ushort4*)(dst + base) = u;
}

// ---------------- gate (fp32 routing, fused x->bf16 convert, NO atomics) ----------------
__global__ __launch_bounds__(256) void gate_kernel(const float* __restrict__ x,
                                                   const float* __restrict__ gw,
                                                   float* __restrict__ wt,
                                                   int* __restrict__ ei,
                                                   unsigned short* __restrict__ xb) {
    __shared__ float xs[DIM];
    __shared__ float lg[8];
    int t = blockIdx.x;
    const float* xrow = x + (size_t)t * DIM;
    for (int i = threadIdx.x; i < DIM / 4; i += 256)
        ((float4*)xs)[i] = ((const float4*)xrow)[i];
    __syncthreads();
    for (int i = threadIdx.x; i < DIM / 4; i += 256) {
        float4 f = ((const float4*)xs)[i];
        ushort4 u;
        u.x = f2bf(f.x); u.y = f2bf(f.y); u.z = f2bf(f.z); u.w = f2bf(f.w);
        ((ushort4*)(xb + (size_t)t * DIM))[i] = u;
    }
    int e = threadIdx.x >> 5;
    int l = threadIdx.x & 31;
    const float* g = gw + (size_t)e * DIM;
    float p = 0.f;
    #pragma unroll 8
    for (int d = l; d < DIM; d += 32) p += xs[d] * g[d];
    for (int m = 16; m >= 1; m >>= 1) p += __shfl_xor(p, m, 32);
    if (l == 0) lg[e] = p;
    __syncthreads();
    if (threadIdx.x == 0) {
        float mx = lg[0];
        for (int i = 1; i < 8; i++) mx = fmaxf(mx, lg[i]);
        float pr[8], s = 0.f;
        for (int i = 0; i < 8; i++) { pr[i] = __expf(lg[i] - mx); s += pr[i]; }
        float inv = 1.f / s;
        float b1 = -1.f, b2 = -1.f; int i1 = 0, i2 = 0;
        for (int i = 0; i < 8; i++) {
            float v = pr[i] * inv;
            if (v > b1)      { b2 = b1; i2 = i1; b1 = v; i1 = i; }
            else if (v > b2) { b2 = v;  i2 = i; }
        }
        wt[t * 3 + 0] = b1; wt[t * 3 + 1] = b2; wt[t * 3 + 2] = 1.f;
        ei[t * 3 + 0] = i1; ei[t * 3 + 1] = i2; ei[t * 3 + 2] = 8;
    }
}

// meta layout: [0..9) counts, [9..18) cursors, [18..27) offsets
__global__ void zero_meta_kernel(int* meta) {
    if (threadIdx.x < 18) meta[threadIdx.x] = 0;
}
// block-aggregated expert counting: 16 blocks x 9 global atomics total
__global__ __launch_bounds__(256) void count_kernel(const int* __restrict__ ei,
                                                    int* __restrict__ meta) {
    __shared__ int lcnt[NE];
    if (threadIdx.x < NE) lcnt[threadIdx.x] = 0;
    __syncthreads();
    int t = blockIdx.x * 256 + threadIdx.x;
    #pragma unroll
    for (int s = 0; s < 3; s++) atomicAdd(&lcnt[ei[t * 3 + s]], 1);
    __syncthreads();
    if (threadIdx.x < NE) atomicAdd(&meta[threadIdx.x], lcnt[threadIdx.x]);
}
__global__ void scan_meta_kernel(int* meta) {
    if (threadIdx.x == 0) {
        int a = 0;
        for (int e = 0; e < NE; e++) { meta[18 + e] = a; a += meta[e]; }
    }
}
// block-aggregated placement; also writes token->slot map for the combine pass
__global__ __launch_bounds__(256) void fill_kernel(const int* __restrict__ ei,
                                                   const float* __restrict__ wt,
                                                   int* __restrict__ meta,
                                                   int* __restrict__ pair_tok,
                                                   float* __restrict__ pair_w,
                                                   int* __restrict__ slots) {
    __shared__ int lcnt[NE], lbase[NE];
    if (threadIdx.x < NE) lcnt[threadIdx.x] = 0;
    __syncthreads();
    int t = blockIdx.x * 256 + threadIdx.x;
    int es[3], lp[3];
    #pragma unroll
    for (int s = 0; s < 3; s++) {
        es[s] = ei[t * 3 + s];
        lp[s] = atomicAdd(&lcnt[es[s]], 1);
    }
    __syncthreads();
    if (threadIdx.x < NE)
        lbase[threadIdx.x] = atomicAdd(&meta[9 + threadIdx.x], lcnt[threadIdx.x]);
    __syncthreads();
    #pragma unroll
    for (int s = 0; s < 3; s++) {
        int g = meta[18 + es[s]] + lbase[es[s]] + lp[s];
        pair_tok[g] = t;
        pair_w[g] = wt[t * 3 + s];
        slots[t * 3 + s] = g;
    }
}

// ---------------- GEMM1: G[p,i] = silu(x.w1^T) * (x.w3^T) * route_w, bf16 out ----------------
// BM=128, BN=64, BK=64, 256 threads (4 waves, 2x2), dual accumulator (w1,w3)
// Grid (r3 ordering, measured best): x = n-block (fastest), y = m-capacity, z = expert.
// All useful blocks co-resident -> A + weights share aggregate L2/L3.
__global__ __launch_bounds__(256) void gemm1_kernel(
        const unsigned short* __restrict__ xb,
        const unsigned short* __restrict__ w1b,
        const unsigned short* __restrict__ w3b,
        unsigned short* __restrict__ G,
        const int* __restrict__ meta,
        const int* __restrict__ pair_tok,
        const float* __restrict__ pair_w) {
    int e = blockIdx.z;
    int cnt = meta[e];
    int m0 = blockIdx.y * 128;
    if (m0 >= cnt) return;
    int off = meta[18 + e];
    int n0 = blockIdx.x * 64;

    __shared__ __align__(16) unsigned short As[128 * 64];
    __shared__ __align__(16) unsigned short B1s[64 * 64];
    __shared__ __align__(16) unsigned short B3s[64 * 64];

    int tid = threadIdx.x;
    int wave = tid >> 6, lane = tid & 63;
    int kc = (lane & 7) ^ (lane >> 3);          // XOR phase: j-invariant

    const unsigned short* gsrcA[8];
    const unsigned short* bbase = nullptr;
    unsigned short* lbase = nullptr;
    if (wave < 2) {
        #pragma unroll
        for (int j = 0; j < 8; j++) {
            int row = (wave * 8 + j) * 8 + (lane >> 3);
            int p = m0 + row; p = p < cnt ? p : cnt - 1;
            int tok = pair_tok[off + p];
            gsrcA[j] = xb + (size_t)tok * DIM + kc * 8;
        }
    } else {
        const unsigned short* wsrc = (wave == 2) ? w1b : w3b;
        lbase = (wave == 2) ? B1s : B3s;
        bbase = wsrc + ((size_t)e * INTER + n0 + (lane >> 3)) * DIM + kc * 8;
    }

    int wm = wave >> 1, wn = wave & 1;
    int mb = wm * 64, nb = wn * 32;
    v4f zero4 = {0.f, 0.f, 0.f, 0.f};
    v4f acc1[4][2], acc3[4][2];
    #pragma unroll
    for (int i = 0; i < 4; i++)
        #pragma unroll
        for (int j = 0; j < 2; j++) { acc1[i][j] = zero4; acc3[i][j] = zero4; }

    for (int k0 = 0; k0 < DIM; k0 += 64) {
        if (wave < 2) {
            #pragma unroll
            for (int j = 0; j < 8; j++)
                gload_lds16(gsrcA[j] + k0, &As[(wave * 8 + j) * 512]);
        } else {
            #pragma unroll
            for (int j = 0; j < 8; j++)
                gload_lds16(bbase + (size_t)j * 8 * DIM + k0, &lbase[j * 512]);
        }
        __syncthreads();
        #pragma unroll
        for (int s = 0; s < 2; s++) {
            int kk = s * 4 + (lane >> 4);
            v8s a[4], b1[2], b3[2];
            #pragma unroll
            for (int mt = 0; mt < 4; mt++) {
                int r = mb + mt * 16 + (lane & 15);
                a[mt] = *(const v8s*)&As[r * 64 + ((kk ^ (r & 7)) << 3)];
            }
            #pragma unroll
            for (int nt = 0; nt < 2; nt++) {
                int n = nb + nt * 16 + (lane & 15);
                int o = n * 64 + ((kk ^ (n & 7)) << 3);
                b1[nt] = *(const v8s*)&B1s[o];
                b3[nt] = *(const v8s*)&B3s[o];
            }
            #pragma unroll
            for (int mt = 0; mt < 4; mt++)
                #pragma unroll
                for (int nt = 0; nt < 2; nt++) {
                    acc1[mt][nt] = __builtin_amdgcn_mfma_f32_16x16x32_bf16(a[mt], b1[nt], acc1[mt][nt], 0, 0, 0);
                    acc3[mt][nt] = __builtin_amdgcn_mfma_f32_16x16x32_bf16(a[mt], b3[nt], acc3[mt][nt], 0, 0, 0);
                }
        }
        __syncthreads();
    }

    #pragma unroll
    for (int mt = 0; mt < 4; mt++) {
        #pragma unroll
        for (int r = 0; r < 4; r++) {
            int row = mb + mt * 16 + ((lane >> 4) << 2) + r;
            int p = m0 + row;
            if (p < cnt) {
                float w = pair_w[off + p];
                size_t gbase = (size_t)(off + p) * INTER + n0 + nb;
                #pragma unroll
                for (int nt = 0; nt < 2; nt++) {
                    float h1 = acc1[mt][nt][r];
                    float h3 = acc3[mt][nt][r];
                    float gv = h1 / (1.f + __expf(-h1)) * h3 * w;
                    G[gbase + nt * 16 + (lane & 15)] = f2bf(gv);
                }
            }
        }
    }
}

// ---------------- GEMM2: eo[p,d] = G[p,:] . w2[e][d,:]  (bf16, non-atomic) ----------------
// BM=128, BN=128, BK=64, 256 threads (4 waves, 2x2); grid: x = n (fastest), y = m-capacity
__global__ __launch_bounds__(256) void gemm2_kernel(
        const unsigned short* __restrict__ G,
        const unsigned short* __restrict__ w2b,
        unsigned short* __restrict__ eo,
        const int* __restrict__ meta) {
    int e = blockIdx.z;
    int cnt = meta[e];
    int m0 = blockIdx.y * 128;
    if (m0 >= cnt) return;
    int off = meta[18 + e];
    int n0 = blockIdx.x * 128;

    __shared__ __align__(16) unsigned short As[128 * 64];
    __shared__ __align__(16) unsigned short Bs[128 * 64];

    int tid = threadIdx.x;
    int wave = tid >> 6, lane = tid & 63;
    int kc = (lane & 7) ^ (lane >> 3);

    const unsigned short* gsrcA[8];
    const unsigned short* bbase = nullptr;
    if (wave < 2) {
        #pragma unroll
        for (int j = 0; j < 8; j++) {
            int row = (wave * 8 + j) * 8 + (lane >> 3);
            int p = m0 + row; p = p < cnt ? p : cnt - 1;
            gsrcA[j] = G + (size_t)(off + p) * INTER + kc * 8;
        }
    } else {
        int g0 = (wave - 2) * 64;
        bbase = w2b + ((size_t)e * DIM + n0 + g0 + (lane >> 3)) * INTER + kc * 8;
    }

    int wm = wave >> 1, wn = wave & 1;
    int mb = wm * 64, nbw = wn * 64;
    v4f zero4 = {0.f, 0.f, 0.f, 0.f};
    v4f acc[4][4];
    #pragma unroll
    for (int i = 0; i < 4; i++)
        #pragma unroll
        for (int j = 0; j < 4; j++) acc[i][j] = zero4;

    for (int k0 = 0; k0 < INTER; k0 += 64) {
        if (wave < 2) {
            #pragma unroll
            for (int j = 0; j < 8; j++)
                gload_lds16(gsrcA[j] + k0, &As[(wave * 8 + j) * 512]);
        } else {
            int g0 = (wave - 2) * 8;
            #pragma unroll
            for (int j = 0; j < 8; j++)
                gload_lds16(bbase + (size_t)j * 8 * INTER + k0, &Bs[(g0 + j) * 512]);
        }
        __syncthreads();
        #pragma unroll
        for (int s = 0; s < 2; s++) {
            int kk = s * 4 + (lane >> 4);
            v8s a[4], b[4];
            #pragma unroll
            for (int mt = 0; mt < 4; mt++) {
                int r = mb + mt * 16 + (lane & 15);
                a[mt] = *(const v8s*)&As[r * 64 + ((kk ^ (r & 7)) << 3)];
            }
            #pragma unroll
            for (int nt = 0; nt < 4; nt++) {
                int n = nbw + nt * 16 + (lane & 15);
                b[nt] = *(const v8s*)&Bs[n * 64 + ((kk ^ (n & 7)) << 3)];
            }
            #pragma unroll
            for (int mt = 0; mt < 4; mt++)
                #pragma unroll
                for (int nt = 0; nt < 4; nt++)
                    acc[mt][nt] = __builtin_amdgcn_mfma_f32_16x16x32_bf16(a[mt], b[nt], acc[mt][nt], 0, 0, 0);
        }
        __syncthreads();
    }

    #pragma unroll
    for (int mt = 0; mt < 4; mt++) {
        #pragma unroll
        for (int r = 0; r < 4; r++) {
            int row = mb + mt * 16 + ((lane >> 4) << 2) + r;
            int p = m0 + row;
            if (p < cnt) {
                unsigned short* obase = eo + (size_t)(off + p) * DIM + n0 + nbw;
                #pragma unroll
                for (int nt = 0; nt < 4; nt++)
                    obase[nt * 16 + (lane & 15)] = f2bf(acc[mt][nt][r]);
            }
        }
    }
}

// ---------------- combine: out[t,:] = eo[p1,:] + eo[p2,:] + eo[p3,:] ----------------
__global__ __launch_bounds__(256) void combine_kernel(const unsigned short* __restrict__ eo,
                                                      const int* __restrict__ slots,
                                                      float* __restrict__ out) {
    int t = blockIdx.x;
    int p0 = slots[t * 3 + 0], p1 = slots[t * 3 + 1], p2 = slots[t * 3 + 2];
    const ushort4* r0 = (const ushort4*)(eo + (size_t)p0 * DIM);
    const ushort4* r1 = (const ushort4*)(eo + (size_t)p1 * DIM);
    const ushort4* r2 = (const ushort4*)(eo + (size_t)p2 * DIM);
    float4* o = (float4*)(out + (size_t)t * DIM);
    for (int i = threadIdx.x; i < DIM / 4; i += 256) {
        ushort4 a = r0[i], b = r1[i], c = r2[i];
        float4 v;
        v.x = __uint_as_float((unsigned)a.x << 16) + __uint_as_float((unsigned)b.x << 16) + __uint_as_float((unsigned)c.x << 16);
        v.y = __uint_as_float((unsigned)a.y << 16) + __uint_as_float((unsigned)b.y << 16) + __uint_as_float((unsigned)c.y << 16);
        v.z = __uint_as_float((unsigned)a.z << 16) + __uint_as_float((unsigned)b.z << 16) + __uint_as_float((unsigned)c.z << 16);
        v.w = __uint_as_float((unsigned)a.w << 16) + __uint_as_float((unsigned)b.w << 16) + __uint_as_float((unsigned)c.w << 16);
        o[i] = v;
    }
}

// ---------------- launch ----------------
extern "C" void kernel_launch(void* const* d_in, const int* in_sizes, int n_in,
                              void* d_out, int out_size, void* d_ws, size_t ws_size,
                              hipStream_t stream) {
    const float* x   = (const float*)d_in[0];
    const float* gw  = (const float*)d_in[1];
    const float* w1  = (const float*)d_in[2];
    const float* w2  = (const float*)d_in[3];
    const float* w3  = (const float*)d_in[4];
    const float* ws1 = (const float*)d_in[5];
    const float* ws2 = (const float*)d_in[6];
    const float* ws3 = (const float*)d_in[7];
    float* out = (float*)d_out;

    char* p = (char*)d_ws;
    auto alloc = [&](size_t bytes) {
        void* r = (void*)p;
        p += (bytes + 255) & ~(size_t)255;
        return r;
    };
    unsigned short* xb  = (unsigned short*)alloc((size_t)T_TOK * DIM * 2);
    unsigned short* w1b = (unsigned short*)alloc((size_t)NE * INTER * DIM * 2);
    unsigned short* w3b = (unsigned short*)alloc((size_t)NE * INTER * DIM * 2);
    unsigned short* w2b = (unsigned short*)alloc((size_t)NE * DIM * INTER * 2);
    unsigned short* G   = (unsigned short*)alloc((size_t)NPAIR * INTER * 2);
    int*   ei    = (int*)alloc((size_t)T_TOK * 3 * 4);
    float* wt    = (float*)alloc((size_t)T_TOK * 3 * 4);
    int*   ptok  = (int*)alloc((size_t)NPAIR * 4);
    float* pw    = (float*)alloc((size_t)NPAIR * 4);
    int*   slots = (int*)alloc((size_t)NPAIR * 4);
    int*   meta  = (int*)alloc(32 * 4);
    // eo (12288 x 2048 bf16 = 50.3 MB) aliases w1b+w3b (75.5 MB): dead after gemm1
    unsigned short* eo = w1b;

    zero_meta_kernel<<<1, 32, 0, stream>>>(meta);
    int wgrid = (NE * INTER * DIM / 4) / 256;   // 18432
    cvt_w_kernel<<<dim3(wgrid, 3), 256, 0, stream>>>(w1, ws1, w1b, w3, ws3, w3b, w2, ws2, w2b);
    gate_kernel<<<T_TOK, 256, 0, stream>>>(x, gw, wt, ei, xb);
    count_kernel<<<T_TOK / 256, 256, 0, stream>>>(ei, meta);
    scan_meta_kernel<<<1, 1, 0, stream>>>(meta);
    fill_kernel<<<T_TOK / 256, 256, 0, stream>>>(ei, wt, meta, ptok, pw, slots);
    gemm1_kernel<<<dim3(INTER / 64, 32, NE), 256, 0, stream>>>(xb, w1b, w3b, G, meta, ptok, pw);
    gemm2_kernel<<<dim3(DIM / 128, 32, NE), 256, 0, stream>>>(G, w2b, eo, meta);
    combine_kernel<<<T_TOK, 256, 0, stream>>>(eo, slots, out);
}